// Round 10
// baseline (157.414 us; speedup 1.0000x reference)
//
#include <hip/hip_runtime.h>
#include <hip/hip_bf16.h>

#define BN 4
#define CN 64
#define ON 64
#define HN 128
#define WN 128
#define HWN (HN*WN)
#define NT 9

typedef __attribute__((ext_vector_type(8))) short bf16x8;
typedef __attribute__((ext_vector_type(4))) float floatx4;

static __device__ __forceinline__ unsigned short f2bf(float f) {
    unsigned int u = __builtin_bit_cast(unsigned int, f);
    u += 0x7fffu + ((u >> 16) & 1u);   // RNE
    return (unsigned short)(u >> 16);
}
static __device__ __forceinline__ float bf2f(short h) {
    unsigned int u = ((unsigned int)(unsigned short)h) << 16;
    return __builtin_bit_cast(float, u);
}

// XCD-aware swizzle for 1024 blocks: XCD k owns works [k*128, k*128+128)
static __device__ __forceinline__ int swz_work(int b) {
    return ((b & 7) << 7) | (b >> 3);
}

// ---------------------------------------------------------------------------
// Kernel T (R5 verbatim, passed): x (B,C,H,W) f32 -> xTh (B,H,W,C) bf16.
// ---------------------------------------------------------------------------
__global__ __launch_bounds__(256) void transpose_kernel(
    const float* __restrict__ x, unsigned short* __restrict__ xTh)
{
    __shared__ float ls[64][65];
    const int tid   = threadIdx.x;
    const int work  = swz_work(blockIdx.x);
    const int pbase = work << 6;
    const int bi    = pbase >> 14;
    const int poff  = pbase & (HWN-1);
    const float* xb = x + (size_t)bi*CN*HWN + poff;
    const int lane = tid & 63, g = tid >> 6;

    #pragma unroll
    for (int k = 0; k < 16; ++k) {
        int c = g*16 + k;
        ls[c][lane] = xb[(size_t)c*HWN + lane];   // coalesced 256B per instr
    }
    __syncthreads();

    unsigned short* dst = xTh + (size_t)pbase*CN;
    #pragma unroll
    for (int j = 0; j < 2; ++j) {
        int u   = j*256 + tid;        // uint4 index, 512 total (8 ch each)
        int p   = u >> 3;
        int c8i = (u & 7)*8;
        unsigned int a = (unsigned int)f2bf(ls[c8i+0][p]) | ((unsigned int)f2bf(ls[c8i+1][p])<<16);
        unsigned int b = (unsigned int)f2bf(ls[c8i+2][p]) | ((unsigned int)f2bf(ls[c8i+3][p])<<16);
        unsigned int c = (unsigned int)f2bf(ls[c8i+4][p]) | ((unsigned int)f2bf(ls[c8i+5][p])<<16);
        unsigned int e = (unsigned int)f2bf(ls[c8i+6][p]) | ((unsigned int)f2bf(ls[c8i+7][p])<<16);
        ((uint4*)dst)[u] = make_uint4(a,b,c,e);
    }
}

// ---------------------------------------------------------------------------
// Kernel A (R1/R3 verbatim, passed twice): lie-weight conv (f32 x) -> Hom ->
// 9 offsets per pixel; also builds wbf[n][o][c] bf16.
// ---------------------------------------------------------------------------
__global__ __launch_bounds__(256) void offsets_kernel(
    const float* __restrict__ x, const float* __restrict__ w_off,
    const float* __restrict__ w_conv,
    const float* __restrict__ P, const float* __restrict__ d,
    const float* __restrict__ Pinv,
    float2* __restrict__ offs, unsigned short* __restrict__ wbf)
{
    const int tid = threadIdx.x;
    __shared__ float swoff[CN*NT];
    __shared__ float sred[4][64];
    __shared__ float sHm[64][10];

    for (int i = tid; i < CN*NT; i += 256) swoff[i] = w_off[i];

    int gid = blockIdx.x * 256 + tid;
    if (gid < ON*CN*NT) {
        int o   = gid / (CN*NT);
        int rem = gid - o*(CN*NT);
        int c   = rem / NT;
        int n   = rem - c*NT;
        wbf[(n*ON + o)*CN + c] = f2bf(w_conv[gid]);
    }

    const int work  = swz_work(blockIdx.x);
    const int pbase = work << 6;
    const int pix   = tid & 63;
    const int cg    = tid >> 6;
    const int p     = pbase + pix;
    const int wi    = p & (WN-1);
    const int hi    = (p >> 7) & (HN-1);
    const int bi    = p >> 14;
    const float* xb   = x + (size_t)bi*CN*HWN + (size_t)(cg*16)*HWN;
    const float* swc0 = &swoff[cg*16*NT];

    __syncthreads();

    float accv = 0.f;
    #pragma unroll
    for (int ky = 0; ky < 3; ++ky) {
        int yy = hi + ky - 1;
        #pragma unroll
        for (int kx = 0; kx < 3; ++kx) {
            int xx = wi + kx - 1;
            bool v  = (yy >= 0) && (yy < HN) && (xx >= 0) && (xx < WN);
            float m = v ? 1.f : 0.f;
            int a   = v ? (yy*WN + xx) : 0;
            const float* swc = swc0 + (ky*3 + kx);
            float t0 = 0.f, t1 = 0.f, t2 = 0.f, t3 = 0.f;
            #pragma unroll
            for (int c = 0; c < 16; c += 4) {
                t0 = fmaf(xb[(size_t)(c+0)*HWN + a], swc[(c+0)*NT], t0);
                t1 = fmaf(xb[(size_t)(c+1)*HWN + a], swc[(c+1)*NT], t1);
                t2 = fmaf(xb[(size_t)(c+2)*HWN + a], swc[(c+2)*NT], t2);
                t3 = fmaf(xb[(size_t)(c+3)*HWN + a], swc[(c+3)*NT], t3);
            }
            accv = fmaf(m, (t0+t1)+(t2+t3), accv);
        }
    }
    sred[cg][pix] = accv;
    __syncthreads();

    if (tid < 64) {
        float raw = (sred[0][tid]+sred[1][tid]) + (sred[2][tid]+sred[3][tid]);
        float lw  = fminf(fmaxf(raw + 0.5f, 0.f), 1.f);
        float pw[3];
        #pragma unroll
        for (int k = 0; k < 3; ++k) pw[k] = exp2f(lw * log2f(d[k]));
        #pragma unroll
        for (int i = 0; i < 3; ++i)
            #pragma unroll
            for (int j = 0; j < 3; ++j)
                sHm[tid][i*3+j] = P[i*3+0]*pw[0]*Pinv[0+j]
                                + P[i*3+1]*pw[1]*Pinv[3+j]
                                + P[i*3+2]*pw[2]*Pinv[6+j];
    }
    __syncthreads();

    for (int e = tid; e < 64*NT; e += 256) {
        int pp = e / NT, n = e - pp*NT;
        float fx = (float)(n % 3) - 1.f;
        float fy = (float)(n / 3) - 1.f;
        float qx = sHm[pp][0]*fx + sHm[pp][1]*fy + sHm[pp][2];
        float qy = sHm[pp][3]*fx + sHm[pp][4]*fy + sHm[pp][5];
        float qz = sHm[pp][6]*fx + sHm[pp][7]*fy + sHm[pp][8];
        float ri = 1.f / qz;
        offs[(size_t)(pbase+pp)*NT + n] = make_float2(qx*ri, qy*ri);
    }
}

// ---------------------------------------------------------------------------
// Kernel B: R3's tap-precompute (offs -> tapB/tapW, verbatim; passed) spliced
// with R5's bf16 gather + MFMA + epilogue (verbatim; passed). No new
// mechanisms: no LDS window, no cross-lane shuffles in the gather.
// ---------------------------------------------------------------------------
#define LDSD 20736   // tapB 2304 | tapW 9216 | sT 9216 (64 x 72 bf16)

__global__ __launch_bounds__(256) void deform_bf16(
    const unsigned short* __restrict__ xTh, const float2* __restrict__ offs,
    const unsigned short* __restrict__ wbf, float* __restrict__ out)
{
    __shared__ __align__(16) char lds[LDSD];
    int*            tapB = (int*)lds;                       // [576] ushort-unit base
    float4*         tapW = (float4*)(lds + 2304);           // [576]
    unsigned short* sT   = (unsigned short*)(lds + 11520);  // [64][72]

    const int tid   = threadIdx.x;
    const int work  = swz_work(blockIdx.x);
    const int pbase = work << 6;
    const int w0    = pbase & (WN-1);
    const int hi    = (pbase >> 7) & (HN-1);
    const int bi    = pbase >> 14;
    const unsigned short* xb = xTh + (size_t)bi * HWN * CN;

    // ---- taps (R3 verbatim): pair-base + clamp-folded slot weights
    for (int e = tid; e < 64*NT; e += 256) {
        int pix = e / NT, n = e - pix*NT;
        float2 off = offs[(size_t)(pbase + pix)*NT + n];
        float px = (float)(w0 + pix) + off.x;
        float py = (float)hi + off.y;
        float x0f = floorf(px), y0f = floorf(py);
        float fx = px - x0f,    fy = py - y0f;
        int ix0 = (int)x0f, iy0 = (int)y0f;
        int bx = min(max(ix0, 0), WN-2);
        int by = min(max(iy0, 0), HN-2);
        float wx0 = 1.f - fx, wx1 = fx;
        float wy0 = 1.f - fy, wy1 = fy;
        float sxL = (ix0   == bx   ? wx0 : 0.f) + (ix0+1 == bx   ? wx1 : 0.f);
        float sxR = (ix0   == bx+1 ? wx0 : 0.f) + (ix0+1 == bx+1 ? wx1 : 0.f);
        float syT = (iy0   == by   ? wy0 : 0.f) + (iy0+1 == by   ? wy1 : 0.f);
        float syB = (iy0   == by+1 ? wy0 : 0.f) + (iy0+1 == by+1 ? wy1 : 0.f);
        tapB[e] = (by*WN + bx)*CN;
        tapW[e] = make_float4(syT*sxL, syT*sxR, syB*sxL, syB*sxR);
    }
    __syncthreads();                      // taps ready; read-only hereafter

    const int lane = tid & 63;
    const int g    = tid >> 6;
    const int p8   = lane & 7;
    const int c8   = lane >> 3;
    const int q    = lane >> 4;
    const int m15  = lane & 15;
    const int mpix = g*16 + m15;

    floatx4 acc[4];
    #pragma unroll
    for (int f = 0; f < 4; ++f) acc[f] = (floatx4){0.f,0.f,0.f,0.f};

    // ---- 9 phases (R5 verbatim): bf16 gather (wave-private sT) + MFMA
    for (int n = 0; n < NT; ++n) {
        #pragma unroll
        for (int i = 0; i < 2; ++i) {
            int bp = g*16 + i*8 + p8;
            int e  = bp*NT + n;
            int tb = tapB[e];
            float4 tw = tapW[e];
            const unsigned short* A = xb + (size_t)tb + c8*8;
            bf16x8 v00 = *(const bf16x8*)A;
            bf16x8 v01 = *(const bf16x8*)(A + CN);
            bf16x8 v10 = *(const bf16x8*)(A + WN*CN);
            bf16x8 v11 = *(const bf16x8*)(A + WN*CN + CN);
            unsigned int pk[4];
            #pragma unroll
            for (int j = 0; j < 8; j += 2) {
                float a0 = fmaf(tw.x, bf2f(v00[j]),
                           fmaf(tw.y, bf2f(v01[j]),
                           fmaf(tw.z, bf2f(v10[j]), tw.w*bf2f(v11[j]))));
                float a1 = fmaf(tw.x, bf2f(v00[j+1]),
                           fmaf(tw.y, bf2f(v01[j+1]),
                           fmaf(tw.z, bf2f(v10[j+1]), tw.w*bf2f(v11[j+1]))));
                pk[j>>1] = (unsigned int)f2bf(a0) | ((unsigned int)f2bf(a1)<<16);
            }
            *(int4*)&sT[bp*72 + c8*8] = make_int4(pk[0],pk[1],pk[2],pk[3]);
        }
        #pragma unroll
        for (int k0 = 0; k0 < 64; k0 += 32) {
            bf16x8 a = *(const bf16x8*)&sT[mpix*72 + k0 + q*8];
            #pragma unroll
            for (int f = 0; f < 4; ++f) {
                bf16x8 bfr = *(const bf16x8*)&wbf[((size_t)(n*ON + f*16 + m15))*CN + k0 + q*8];
                acc[f] = __builtin_amdgcn_mfma_f32_16x16x32_bf16(a, bfr, acc[f], 0, 0, 0);
            }
        }
    }

    // ---- epilogue (R5 verbatim): transpose through LDS for coalesced stores
    __syncthreads();
    float* tr = (float*)lds;             // [64 o][72 pix] over dead tap/sT
    #pragma unroll
    for (int f = 0; f < 4; ++f) {
        int o = f*16 + m15;
        #pragma unroll
        for (int r = 0; r < 4; ++r) {
            int pix = g*16 + q*4 + r;    // C/D layout: row=(lane>>4)*4+reg
            tr[o*72 + pix] = acc[f][r];
        }
    }
    __syncthreads();
    const int og = tid >> 6;
    float* ob = out + (((size_t)bi*ON)*HN + hi)*WN + w0;
    #pragma unroll
    for (int j = 0; j < 16; ++j) {
        int o = og*16 + j;
        ob[(size_t)o*HWN + lane] = tr[o*72 + lane];
    }
}

// ---------------------------------------------------------------------------
extern "C" void kernel_launch(void* const* d_in, const int* in_sizes, int n_in,
                              void* d_out, int out_size, void* d_ws, size_t ws_size,
                              hipStream_t stream) {
    const float* x      = (const float*)d_in[0];
    const float* w_off  = (const float*)d_in[1];
    const float* w_conv = (const float*)d_in[2];
    const float* P      = (const float*)d_in[3];
    const float* d      = (const float*)d_in[4];
    const float* Pinv   = (const float*)d_in[5];
    float* out = (float*)d_out;

    const size_t XTH_BYTES  = (size_t)BN*HN*WN*CN*2;   // 8388608
    const size_t OFFS_BYTES = (size_t)BN*HWN*NT*8;     // 4718592

    unsigned short* xTh = (unsigned short*)d_ws;
    float2* offs = (float2*)((char*)d_ws + XTH_BYTES);
    unsigned short* wbf = (unsigned short*)((char*)d_ws + XTH_BYTES + OFFS_BYTES);

    transpose_kernel<<<1024, 256, 0, stream>>>(x, xTh);
    offsets_kernel<<<1024, 256, 0, stream>>>(x, w_off, w_conv, P, d, Pinv, offs, wbf);
    deform_bf16<<<1024, 256, 0, stream>>>(xTh, offs, wbf, out);
}

// Round 11
// 151.004 us; speedup vs baseline: 1.0424x; 1.0424x over previous
//
#include <hip/hip_runtime.h>
#include <hip/hip_bf16.h>

#define BN 4
#define CN 64
#define ON 64
#define HN 128
#define WN 128
#define HWN (HN*WN)
#define NT 9

typedef __attribute__((ext_vector_type(8))) short bf16x8;
typedef __attribute__((ext_vector_type(4))) float floatx4;

static __device__ __forceinline__ unsigned short f2bf(float f) {
    unsigned int u = __builtin_bit_cast(unsigned int, f);
    u += 0x7fffu + ((u >> 16) & 1u);   // RNE
    return (unsigned short)(u >> 16);
}

// XCD-aware swizzle for 1024 blocks: XCD k owns works [k*128, k*128+128)
static __device__ __forceinline__ int swz_work(int b) {
    return ((b & 7) << 7) | (b >> 3);
}

// ---------------------------------------------------------------------------
// Kernel TO (fused transpose + offsets): stage 3 half-rows x 64ch x 66cols
// f32 in LDS (block-private, R2-verified staging class); write center row to
// xT (B,H,W,C) f32 (exact copy); conv with R1-verbatim FMA order from LDS;
// Hom -> offs R1-verbatim; wbf build R1-verbatim.
// ---------------------------------------------------------------------------
__global__ __launch_bounds__(256) void to_kernel(
    const float* __restrict__ x, const float* __restrict__ w_off,
    const float* __restrict__ w_conv,
    const float* __restrict__ P, const float* __restrict__ d,
    const float* __restrict__ Pinv,
    float* __restrict__ xT, float2* __restrict__ offs,
    unsigned short* __restrict__ wbf)
{
    __shared__ float ls[3][64][68];    // 52224 B; col 0 = image col w0-1
    __shared__ float swoff[CN*NT];     // 2304 B
    __shared__ float sred[4][64];      // 1024 B
    __shared__ float sHm[64][10];      // 2560 B

    const int tid = threadIdx.x;
    for (int i = tid; i < CN*NT; i += 256) swoff[i] = w_off[i];

    // wbf build (R1 verbatim): first 36864 global threads
    int gid = blockIdx.x * 256 + tid;
    if (gid < ON*CN*NT) {
        int o   = gid / (CN*NT);
        int rem = gid - o*(CN*NT);
        int c   = rem / NT;
        int n   = rem - c*NT;
        wbf[(n*ON + o)*CN + c] = f2bf(w_conv[gid]);
    }

    const int work  = swz_work(blockIdx.x);
    const int pbase = work << 6;
    const int w0    = pbase & (WN-1);
    const int hi    = (pbase >> 7) & (HN-1);
    const int bi    = pbase >> 14;
    const float* xb = x + (size_t)bi * CN * HWN;

    // ---- stage 3 rows (hi-1, hi, hi+1 clamped) x 64 ch x 66 cols (w0-1..w0+64)
    #pragma unroll
    for (int r = 0; r < 3; ++r) {
        int yy = min(max(hi - 1 + r, 0), HN - 1);
        const float* rowp = xb + (size_t)yy * WN;
        for (int j = tid; j < 64*66; j += 256) {
            int c   = j / 66;
            int col = j - c*66;
            int xg  = min(max(w0 - 1 + col, 0), WN - 1);
            ls[r][c][col] = rowp[(size_t)c*HWN + xg];
        }
    }
    __syncthreads();

    // ---- xT store (R3 transpose writer pattern; center row, col offset +1)
    {
        float4* dst = (float4*)(xT + (size_t)pbase*CN);
        #pragma unroll
        for (int j = 0; j < 4; ++j) {
            int f4 = j*256 + tid;          // 0..1023 float4s
            int p  = f4 >> 4;
            int c4 = (f4 & 15)*4;
            dst[f4] = make_float4(ls[1][c4+0][p+1], ls[1][c4+1][p+1],
                                  ls[1][c4+2][p+1], ls[1][c4+3][p+1]);
        }
    }

    // ---- conv (R1-verbatim arithmetic; source = LDS)
    {
        const int pix = tid & 63;
        const int cg  = tid >> 6;
        const int wi  = w0 + pix;
        const float* swc0 = &swoff[cg*16*NT];
        float accv = 0.f;
        #pragma unroll
        for (int ky = 0; ky < 3; ++ky) {
            int yy = hi + ky - 1;
            #pragma unroll
            for (int kx = 0; kx < 3; ++kx) {
                int xx = wi + kx - 1;
                bool v  = (yy >= 0) && (yy < HN) && (xx >= 0) && (xx < WN);
                float m = v ? 1.f : 0.f;
                int lcol = pix + kx;                  // LDS col for xx (clamped load)
                const float* swc = swc0 + (ky*3 + kx);
                float t0 = 0.f, t1 = 0.f, t2 = 0.f, t3 = 0.f;
                #pragma unroll
                for (int c = 0; c < 16; c += 4) {
                    t0 = fmaf(ls[ky][cg*16 + c+0][lcol], swc[(c+0)*NT], t0);
                    t1 = fmaf(ls[ky][cg*16 + c+1][lcol], swc[(c+1)*NT], t1);
                    t2 = fmaf(ls[ky][cg*16 + c+2][lcol], swc[(c+2)*NT], t2);
                    t3 = fmaf(ls[ky][cg*16 + c+3][lcol], swc[(c+3)*NT], t3);
                }
                accv = fmaf(m, (t0+t1)+(t2+t3), accv);
            }
        }
        sred[cg][pix] = accv;
    }
    __syncthreads();

    // ---- Hom (R1 verbatim)
    if (tid < 64) {
        float raw = (sred[0][tid]+sred[1][tid]) + (sred[2][tid]+sred[3][tid]);
        float lw  = fminf(fmaxf(raw + 0.5f, 0.f), 1.f);
        float pw[3];
        #pragma unroll
        for (int k = 0; k < 3; ++k) pw[k] = exp2f(lw * log2f(d[k]));
        #pragma unroll
        for (int i = 0; i < 3; ++i)
            #pragma unroll
            for (int j = 0; j < 3; ++j)
                sHm[tid][i*3+j] = P[i*3+0]*pw[0]*Pinv[0+j]
                                + P[i*3+1]*pw[1]*Pinv[3+j]
                                + P[i*3+2]*pw[2]*Pinv[6+j];
    }
    __syncthreads();

    // ---- offs write (R1 verbatim)
    for (int e = tid; e < 64*NT; e += 256) {
        int pp = e / NT, n = e - pp*NT;
        float fx = (float)(n % 3) - 1.f;
        float fy = (float)(n / 3) - 1.f;
        float qx = sHm[pp][0]*fx + sHm[pp][1]*fy + sHm[pp][2];
        float qy = sHm[pp][3]*fx + sHm[pp][4]*fy + sHm[pp][5];
        float qz = sHm[pp][6]*fx + sHm[pp][7]*fy + sHm[pp][8];
        float ri = 1.f / qz;
        offs[(size_t)(pbase+pp)*NT + n] = make_float2(qx*ri, qy*ri);
    }
}

// ---------------------------------------------------------------------------
// Kernel B (R3 verbatim, passed at 58.5us): gather from channel-contiguous
// xT f32 with float4 loads; wave-private sT; no barriers in the n-loop.
// ---------------------------------------------------------------------------
#define LDSB 20736   // tapB 2304 | tapW 9216 | sT 9216 (64 x 72 bf16)

__global__ __launch_bounds__(256) void deform_xt(
    const float* __restrict__ xT, const float2* __restrict__ offs,
    const unsigned short* __restrict__ wbf, float* __restrict__ out)
{
    __shared__ __align__(16) char lds[LDSB];
    int*            tapB = (int*)lds;                       // [576] dword base
    float4*         tapW = (float4*)(lds + 2304);           // [576]
    unsigned short* sT   = (unsigned short*)(lds + 11520);  // [64][72]

    const int tid   = threadIdx.x;
    const int work  = swz_work(blockIdx.x);
    const int pbase = work << 6;
    const int w0    = pbase & (WN-1);
    const int hi    = (pbase >> 7) & (HN-1);
    const int bi    = pbase >> 14;
    const float* xTb = xT + (size_t)bi * HWN * CN;

    // ---- taps: pair-base (by,bx in [0,126]) + slot weights, clamp folded in
    for (int e = tid; e < 64*NT; e += 256) {
        int pix = e / NT, n = e - pix*NT;
        float2 off = offs[(size_t)(pbase + pix)*NT + n];
        float px = (float)(w0 + pix) + off.x;
        float py = (float)hi + off.y;
        float x0f = floorf(px), y0f = floorf(py);
        float fx = px - x0f,    fy = py - y0f;
        int ix0 = (int)x0f, iy0 = (int)y0f;
        int bx = min(max(ix0, 0), WN-2);
        int by = min(max(iy0, 0), HN-2);
        float wx0 = 1.f - fx, wx1 = fx;
        float wy0 = 1.f - fy, wy1 = fy;
        float sxL = (ix0   == bx   ? wx0 : 0.f) + (ix0+1 == bx   ? wx1 : 0.f);
        float sxR = (ix0   == bx+1 ? wx0 : 0.f) + (ix0+1 == bx+1 ? wx1 : 0.f);
        float syT = (iy0   == by   ? wy0 : 0.f) + (iy0+1 == by   ? wy1 : 0.f);
        float syB = (iy0   == by+1 ? wy0 : 0.f) + (iy0+1 == by+1 ? wy1 : 0.f);
        tapB[e] = (by*WN + bx)*CN;
        tapW[e] = make_float4(syT*sxL, syT*sxR, syB*sxL, syB*sxR);
    }
    __syncthreads();                      // taps ready; read-only hereafter

    const int lane = tid & 63;
    const int g    = tid >> 6;
    const int q    = lane >> 4;
    const int m15  = lane & 15;
    const int mpix = g*16 + m15;
    const int psub = lane >> 4;           // pixel-subgroup 0..3
    const int k4   = (lane & 15)*4;       // channel quad

    floatx4 acc[4];
    #pragma unroll
    for (int f = 0; f < 4; ++f) acc[f] = (floatx4){0.f,0.f,0.f,0.f};

    for (int n = 0; n < NT; ++n) {
        // gather: wave g fills sT rows g*16..g*16+15 (wave-private, no barrier)
        #pragma unroll 2
        for (int s = 0; s < 4; ++s) {
            int p = g*16 + s*4 + psub;
            int e = p*NT + n;
            int tb = tapB[e];
            float4 tw = tapW[e];
            const float* A = xTb + tb + k4;
            float4 v00 = *(const float4*)A;
            float4 v01 = *(const float4*)(A + CN);
            float4 v10 = *(const float4*)(A + WN*CN);
            float4 v11 = *(const float4*)(A + WN*CN + CN);
            float rx = fmaf(tw.x,v00.x, fmaf(tw.y,v01.x, fmaf(tw.z,v10.x, tw.w*v11.x)));
            float ry = fmaf(tw.x,v00.y, fmaf(tw.y,v01.y, fmaf(tw.z,v10.y, tw.w*v11.y)));
            float rz = fmaf(tw.x,v00.z, fmaf(tw.y,v01.z, fmaf(tw.z,v10.z, tw.w*v11.z)));
            float rw = fmaf(tw.x,v00.w, fmaf(tw.y,v01.w, fmaf(tw.z,v10.w, tw.w*v11.w)));
            unsigned int u0 = (unsigned int)f2bf(rx) | ((unsigned int)f2bf(ry) << 16);
            unsigned int u1 = (unsigned int)f2bf(rz) | ((unsigned int)f2bf(rw) << 16);
            *(uint2*)&sT[p*72 + k4] = make_uint2(u0, u1);
        }
        // MFMA on this wave's own rows (compiler inserts lgkmcnt for sT dep)
        #pragma unroll
        for (int k0 = 0; k0 < 64; k0 += 32) {
            bf16x8 a = *(const bf16x8*)&sT[mpix*72 + k0 + q*8];
            #pragma unroll
            for (int f = 0; f < 4; ++f) {
                bf16x8 bfr = *(const bf16x8*)&wbf[((size_t)(n*ON + f*16 + m15))*CN + k0 + q*8];
                acc[f] = __builtin_amdgcn_mfma_f32_16x16x32_bf16(a, bfr, acc[f], 0, 0, 0);
            }
        }
    }

    // ---- epilogue: transpose through LDS for coalesced stores
    __syncthreads();
    float* tr = (float*)lds;             // [64 o][72 pix] over dead tap/sT
    #pragma unroll
    for (int f = 0; f < 4; ++f) {
        int o = f*16 + m15;
        #pragma unroll
        for (int r = 0; r < 4; ++r) {
            int pix = g*16 + q*4 + r;    // C/D layout: row=(lane>>4)*4+reg
            tr[o*72 + pix] = acc[f][r];
        }
    }
    __syncthreads();
    const int og = tid >> 6;
    float* ob = out + (((size_t)bi*ON)*HN + hi)*WN + w0;
    #pragma unroll
    for (int j = 0; j < 16; ++j) {
        int o = og*16 + j;
        ob[(size_t)o*HWN + lane] = tr[o*72 + lane];
    }
}

// ---------------------------------------------------------------------------
extern "C" void kernel_launch(void* const* d_in, const int* in_sizes, int n_in,
                              void* d_out, int out_size, void* d_ws, size_t ws_size,
                              hipStream_t stream) {
    const float* x      = (const float*)d_in[0];
    const float* w_off  = (const float*)d_in[1];
    const float* w_conv = (const float*)d_in[2];
    const float* P      = (const float*)d_in[3];
    const float* d      = (const float*)d_in[4];
    const float* Pinv   = (const float*)d_in[5];
    float* out = (float*)d_out;

    const size_t XT_BYTES   = (size_t)BN*HN*WN*CN*4;   // 16777216
    const size_t OFFS_BYTES = (size_t)BN*HWN*NT*8;     // 4718592

    float*  xT  = (float*)d_ws;
    float2* offs = (float2*)((char*)d_ws + XT_BYTES);
    unsigned short* wbf = (unsigned short*)((char*)d_ws + XT_BYTES + OFFS_BYTES);

    to_kernel<<<1024, 256, 0, stream>>>(x, w_off, w_conv, P, d, Pinv, xT, offs, wbf);
    deform_xt<<<1024, 256, 0, stream>>>(xT, offs, wbf, out);
}